// Round 1
// baseline (997.160 us; speedup 1.0000x reference)
//
#include <hip/hip_runtime.h>
#include <hip/hip_bf16.h>
#include <cstdint>

// GraphSAGE 3-layer + edge predictor, restructured:
//   segment_sum(concat(h[src],e)@Wm.T + bm, dst)
//     = g@Wmh.T + eagg@Wme.T + deg*bm,   g = segsum(h[src]), eagg = segsum(e)
// eagg/deg are layer-independent -> computed once. All GEMMs are N-scale fp32.

static inline int cdiv(int a, int b) { return (a + b - 1) / b; }

// ---------------- CSR build ----------------
__global__ __launch_bounds__(256) void k_hist(const int* __restrict__ dst,
                                              int* __restrict__ cnt, int E) {
  int e = blockIdx.x * 256 + threadIdx.x;
  if (e < E) atomicAdd(&cnt[dst[e]], 1);
}

__global__ __launch_bounds__(1024) void k_scan(const int* __restrict__ cnt,
                                               int* __restrict__ offs, int n) {
  __shared__ int tmp[1024];
  int t = threadIdx.x;
  int running = 0;
  if (t == 0) offs[0] = 0;
  for (int base = 0; base < n; base += 1024) {
    int i = base + t;
    int v = (i < n) ? cnt[i] : 0;
    tmp[t] = v;
    __syncthreads();
    for (int ofs = 1; ofs < 1024; ofs <<= 1) {
      int add = (t >= ofs) ? tmp[t - ofs] : 0;
      __syncthreads();
      tmp[t] += add;
      __syncthreads();
    }
    if (i < n) offs[i + 1] = running + tmp[t];
    running += tmp[1023];
    __syncthreads();
  }
}

__global__ __launch_bounds__(256) void k_scatter(const int* __restrict__ src,
                                                 const int* __restrict__ dst,
                                                 const int* __restrict__ offs,
                                                 int* __restrict__ fill,
                                                 int* __restrict__ csr_edge,
                                                 int* __restrict__ csr_src, int E) {
  int e = blockIdx.x * 256 + threadIdx.x;
  if (e < E) {
    int d = dst[e];
    int pos = offs[d] + atomicAdd(&fill[d], 1);
    csr_edge[pos] = e;
    csr_src[pos] = src[e];
  }
}

// ---------------- weight transposes: W[dout][K] -> WT[K][dout] ----------------
__global__ __launch_bounds__(256) void k_transpose(const float* __restrict__ W,
                                                   float* __restrict__ WT,
                                                   int dout, int K) {
  int i = blockIdx.x * 256 + threadIdx.x;
  if (i >= K * dout) return;
  int k = i / dout, o = i - k * dout;
  WT[i] = W[o * K + k];
}

// Wp[15][256] -> WpT2[128][30]: col c<15 = Wp[c][k] (src half), c>=15 = Wp[c-15][128+k]
__global__ __launch_bounds__(256) void k_wpT(const float* __restrict__ Wp,
                                             float* __restrict__ WpT2) {
  int i = blockIdx.x * 256 + threadIdx.x;
  if (i >= 128 * 30) return;
  int k = i / 30, c = i - k * 30;
  WpT2[i] = (c < 15) ? Wp[c * 256 + k] : Wp[(c - 15) * 256 + 128 + k];
}

// ---------------- segment sums via CSR (one wave per node) ----------------
__global__ __launch_bounds__(64) void k_eagg(const float* __restrict__ efeats,
                                             const int* __restrict__ csr_edge,
                                             const int* __restrict__ offs,
                                             float* __restrict__ eagg,
                                             float* __restrict__ deg) {
  int d = blockIdx.x, lane = threadIdx.x;
  int s = offs[d], t = offs[d + 1];
  float2 acc = make_float2(0.f, 0.f);
  for (int j = s; j < t; ++j) {
    int e = csr_edge[j];
    float2 v = *reinterpret_cast<const float2*>(efeats + (size_t)e * 128 + lane * 2);
    acc.x += v.x;
    acc.y += v.y;
  }
  *reinterpret_cast<float2*>(eagg + (size_t)d * 128 + lane * 2) = acc;
  if (lane == 0) deg[d] = (float)(t - s);
}

template <int DIN>
__global__ __launch_bounds__(64) void k_gather(const float* __restrict__ h,
                                               const int* __restrict__ csr_src,
                                               const int* __restrict__ offs,
                                               float* __restrict__ g) {
  constexpr int NV = (DIN + 63) / 64;
  int d = blockIdx.x, lane = threadIdx.x;
  float acc[NV];
#pragma unroll
  for (int v = 0; v < NV; ++v) acc[v] = 0.f;
  int s = offs[d], t = offs[d + 1];
  for (int j = s; j < t; ++j) {
    int sn = csr_src[j];
    const float* row = h + (size_t)sn * DIN;
#pragma unroll
    for (int v = 0; v < NV; ++v) {
      int k = lane + 64 * v;
      if (k < DIN) acc[v] += row[k];
    }
  }
#pragma unroll
  for (int v = 0; v < NV; ++v) {
    int k = lane + 64 * v;
    if (k < DIN) g[(size_t)d * DIN + k] = acc[v];
  }
}

// ---------------- fused node GEMM ----------------
// Y[d][o] = post( sum_k A[d][k]*WT[k][o] + sum_k B[d][k]*WT[KA+k][o] )
// MODE 0: msg  -> y = acc/max(deg,1) + bias*(deg>0)
// MODE 1: apply-> y = relu(acc + bias)
// MODE 2: plain-> y = acc
// block (64,4): wave = 1 node-pair row-slab x 128 outputs (2 per lane, float2 W loads).
template <int MODE>
__global__ __launch_bounds__(256) void k_gemm(const float* __restrict__ A, int KA,
                                              const float* __restrict__ B, int KB,
                                              const float* __restrict__ WT,
                                              const float* __restrict__ bias,
                                              const float* __restrict__ deg,
                                              float* __restrict__ Y, int dout, int n) {
  int tx = threadIdx.x, ty = threadIdx.y;
  int o0 = blockIdx.x * 128 + tx * 2;
  int d0 = (blockIdx.y * 4 + ty) * 2;
  if (d0 >= n || o0 >= dout) return;  // dout is even in all uses -> o0+1 valid
  int d1 = (d0 + 1 < n) ? d0 + 1 : d0;
  float acc00 = 0.f, acc01 = 0.f, acc10 = 0.f, acc11 = 0.f;
  {
    const float* a0 = A + (size_t)d0 * KA;
    const float* a1 = A + (size_t)d1 * KA;
    const float* w = WT + o0;
#pragma unroll 4
    for (int k = 0; k < KA; ++k) {
      float2 wv = *reinterpret_cast<const float2*>(w + (size_t)k * dout);
      float x0 = a0[k], x1 = a1[k];
      acc00 = fmaf(x0, wv.x, acc00);
      acc01 = fmaf(x0, wv.y, acc01);
      acc10 = fmaf(x1, wv.x, acc10);
      acc11 = fmaf(x1, wv.y, acc11);
    }
  }
  if (B != nullptr) {
    const float* b0 = B + (size_t)d0 * KB;
    const float* b1 = B + (size_t)d1 * KB;
    const float* w = WT + (size_t)KA * dout + o0;
#pragma unroll 4
    for (int k = 0; k < KB; ++k) {
      float2 wv = *reinterpret_cast<const float2*>(w + (size_t)k * dout);
      float x0 = b0[k], x1 = b1[k];
      acc00 = fmaf(x0, wv.x, acc00);
      acc01 = fmaf(x0, wv.y, acc01);
      acc10 = fmaf(x1, wv.x, acc10);
      acc11 = fmaf(x1, wv.y, acc11);
    }
  }
  float y00, y01, y10, y11;
  if constexpr (MODE == 0) {
    float dg0 = deg[d0], dg1 = deg[d1];
    float s0 = 1.0f / fmaxf(dg0, 1.0f), s1 = 1.0f / fmaxf(dg1, 1.0f);
    float e0 = dg0 > 0.f ? 1.f : 0.f, e1 = dg1 > 0.f ? 1.f : 0.f;
    float bv0 = bias[o0], bv1 = bias[o0 + 1];
    y00 = acc00 * s0 + bv0 * e0;
    y01 = acc01 * s0 + bv1 * e0;
    y10 = acc10 * s1 + bv0 * e1;
    y11 = acc11 * s1 + bv1 * e1;
  } else if constexpr (MODE == 1) {
    float bv0 = bias[o0], bv1 = bias[o0 + 1];
    y00 = fmaxf(acc00 + bv0, 0.f);
    y01 = fmaxf(acc01 + bv1, 0.f);
    y10 = fmaxf(acc10 + bv0, 0.f);
    y11 = fmaxf(acc11 + bv1, 0.f);
  } else {
    y00 = acc00; y01 = acc01; y10 = acc10; y11 = acc11;
  }
  float* y0p = Y + (size_t)d0 * dout + o0;
  y0p[0] = y00;
  y0p[1] = y01;
  if (d1 != d0) {
    float* y1p = Y + (size_t)d1 * dout + o0;
    y1p[0] = y10;
    y1p[1] = y11;
  }
}

// ---------------- edge output ----------------
__global__ __launch_bounds__(256) void k_edge_out(const int* __restrict__ src,
                                                  const int* __restrict__ dst,
                                                  const float* __restrict__ hsd,
                                                  const float* __restrict__ bp,
                                                  float* __restrict__ out, int E) {
  int i = blockIdx.x * 256 + threadIdx.x;
  if (i >= E * 15) return;
  int e = i / 15, c = i - e * 15;
  out[i] = hsd[(size_t)src[e] * 30 + c] + hsd[(size_t)dst[e] * 30 + 15 + c] + bp[c];
}

extern "C" void kernel_launch(void* const* d_in, const int* in_sizes, int n_in,
                              void* d_out, int out_size, void* d_ws, size_t ws_size,
                              hipStream_t stream) {
  const int N = 10000, E = 320000;
  const float* nfeats = (const float*)d_in[0];
  const float* efeats = (const float*)d_in[1];
  const int* src = (const int*)d_in[2];
  const int* dst = (const int*)d_in[3];
  const float* Wm1 = (const float*)d_in[4];
  const float* bm1 = (const float*)d_in[5];
  const float* Wa1 = (const float*)d_in[6];
  const float* ba1 = (const float*)d_in[7];
  const float* Wm2 = (const float*)d_in[8];
  const float* bm2 = (const float*)d_in[9];
  const float* Wa2 = (const float*)d_in[10];
  const float* ba2 = (const float*)d_in[11];
  const float* Wm3 = (const float*)d_in[12];
  const float* bm3 = (const float*)d_in[13];
  const float* Wa3 = (const float*)d_in[14];
  const float* ba3 = (const float*)d_in[15];
  const float* Wp = (const float*)d_in[16];
  const float* bp = (const float*)d_in[17];
  float* out = (float*)d_out;

  char* base = (char*)d_ws;
  size_t woff = 0;
  auto alloc = [&](size_t bytes) -> void* {
    void* p = base + woff;
    woff += (bytes + 255) & ~(size_t)255;
    return p;
  };
  int* cnt = (int*)alloc((size_t)N * 4);
  int* fill = (int*)alloc((size_t)N * 4);
  int* offs = (int*)alloc((size_t)(N + 1) * 4);
  int* csr_edge = (int*)alloc((size_t)E * 4);
  int* csr_src = (int*)alloc((size_t)E * 4);
  float* deg = (float*)alloc((size_t)N * 4);
  float* eagg = (float*)alloc((size_t)N * 128 * 4);
  float* hA = (float*)alloc((size_t)N * 152 * 4);
  float* hB = (float*)alloc((size_t)N * 152 * 4);
  float* g = (float*)alloc((size_t)N * 152 * 4);
  float* nmean = (float*)alloc((size_t)N * 152 * 4);
  float* hsd = (float*)alloc((size_t)N * 30 * 4);
  float* WmT1 = (float*)alloc((256 * 152 + 8) * 4);
  float* WaT1 = (float*)alloc((280 * 152 + 8) * 4);
  float* WmT2 = (float*)alloc((280 * 152 + 8) * 4);
  float* WaT2 = (float*)alloc((304 * 152 + 8) * 4);
  float* WmT3 = (float*)alloc((280 * 128 + 8) * 4);
  float* WaT3 = (float*)alloc((280 * 128 + 8) * 4);
  float* WpT2 = (float*)alloc((128 * 30 + 8) * 4);

  hipMemsetAsync(cnt, 0, (size_t)N * 4, stream);
  hipMemsetAsync(fill, 0, (size_t)N * 4, stream);

  // CSR build
  k_hist<<<cdiv(E, 256), 256, 0, stream>>>(dst, cnt, E);
  k_scan<<<1, 1024, 0, stream>>>(cnt, offs, N);
  k_scatter<<<cdiv(E, 256), 256, 0, stream>>>(src, dst, offs, fill, csr_edge, csr_src, E);

  // weight transposes (tiny)
  k_transpose<<<cdiv(256 * 152, 256), 256, 0, stream>>>(Wm1, WmT1, 152, 256);
  k_transpose<<<cdiv(280 * 152, 256), 256, 0, stream>>>(Wa1, WaT1, 152, 280);
  k_transpose<<<cdiv(280 * 152, 256), 256, 0, stream>>>(Wm2, WmT2, 152, 280);
  k_transpose<<<cdiv(304 * 152, 256), 256, 0, stream>>>(Wa2, WaT2, 152, 304);
  k_transpose<<<cdiv(280 * 128, 256), 256, 0, stream>>>(Wm3, WmT3, 128, 280);
  k_transpose<<<cdiv(280 * 128, 256), 256, 0, stream>>>(Wa3, WaT3, 128, 280);
  k_wpT<<<cdiv(128 * 30, 256), 256, 0, stream>>>(Wp, WpT2);

  // layer-independent edge-feature aggregation (the only big HBM read)
  k_eagg<<<N, 64, 0, stream>>>(efeats, csr_edge, offs, eagg, deg);

  dim3 blk(64, 4, 1);
  dim3 grd152(cdiv(152, 128), cdiv(N, 8));
  dim3 grd128(1, cdiv(N, 8));

  // layer 1: din=128 -> 152
  k_gather<128><<<N, 64, 0, stream>>>(nfeats, csr_src, offs, g);
  k_gemm<0><<<grd152, blk, 0, stream>>>(g, 128, eagg, 128, WmT1, bm1, deg, nmean, 152, N);
  k_gemm<1><<<grd152, blk, 0, stream>>>(nfeats, 128, nmean, 152, WaT1, ba1, nullptr, hA, 152, N);
  // layer 2: 152 -> 152
  k_gather<152><<<N, 64, 0, stream>>>(hA, csr_src, offs, g);
  k_gemm<0><<<grd152, blk, 0, stream>>>(g, 152, eagg, 128, WmT2, bm2, deg, nmean, 152, N);
  k_gemm<1><<<grd152, blk, 0, stream>>>(hA, 152, nmean, 152, WaT2, ba2, nullptr, hB, 152, N);
  // layer 3: 152 -> 128
  k_gather<152><<<N, 64, 0, stream>>>(hB, csr_src, offs, g);
  k_gemm<0><<<grd128, blk, 0, stream>>>(g, 152, eagg, 128, WmT3, bm3, deg, nmean, 128, N);
  k_gemm<1><<<grd128, blk, 0, stream>>>(hB, 152, nmean, 128, WaT3, ba3, nullptr, hA, 128, N);

  // edge predictor: hsd[n] = [h@Wp_src.T | h@Wp_dst.T], then gather-add per edge
  k_gemm<2><<<grd128, blk, 0, stream>>>(hA, 128, nullptr, 0, WpT2, nullptr, nullptr, hsd, 30, N);
  k_edge_out<<<cdiv(E * 15, 256), 256, 0, stream>>>(src, dst, hsd, bp, out, E);
}

// Round 2
// 587.083 us; speedup vs baseline: 1.6985x; 1.6985x over previous
//
#include <hip/hip_runtime.h>
#include <hip/hip_bf16.h>
#include <cstdint>

// GraphSAGE 3-layer + edge predictor, restructured:
//   segment_sum(concat(h[src],e)@Wm.T + bm, dst)
//     = g@Wmh.T + eagg@Wme.T + deg*bm,   g = segsum(h[src]), eagg = segsum(e)
// eagg/deg are layer-independent. GEMMs: 1-wave LDS-tiled 64x64x8, 8x8 micro.

static inline int cdiv(int a, int b) { return (a + b - 1) / b; }

// ---------------- CSR build ----------------
__global__ __launch_bounds__(256) void k_hist(const int* __restrict__ dst,
                                              int* __restrict__ cnt, int E) {
  int e = blockIdx.x * 256 + threadIdx.x;
  if (e < E) atomicAdd(&cnt[dst[e]], 1);
}

__global__ __launch_bounds__(1024) void k_scan(const int* __restrict__ cnt,
                                               int* __restrict__ offs, int n) {
  __shared__ int tmp[1024];
  int t = threadIdx.x;
  int running = 0;
  if (t == 0) offs[0] = 0;
  for (int base = 0; base < n; base += 1024) {
    int i = base + t;
    int v = (i < n) ? cnt[i] : 0;
    tmp[t] = v;
    __syncthreads();
    for (int ofs = 1; ofs < 1024; ofs <<= 1) {
      int add = (t >= ofs) ? tmp[t - ofs] : 0;
      __syncthreads();
      tmp[t] += add;
      __syncthreads();
    }
    if (i < n) offs[i + 1] = running + tmp[t];
    running += tmp[1023];
    __syncthreads();
  }
}

__global__ __launch_bounds__(256) void k_scatter(const int* __restrict__ src,
                                                 const int* __restrict__ dst,
                                                 const int* __restrict__ offs,
                                                 int* __restrict__ fill,
                                                 int* __restrict__ csr_edge,
                                                 int* __restrict__ csr_src, int E) {
  int e = blockIdx.x * 256 + threadIdx.x;
  if (e < E) {
    int d = dst[e];
    int pos = offs[d] + atomicAdd(&fill[d], 1);
    csr_edge[pos] = e;
    csr_src[pos] = src[e];
  }
}

// ---------------- weight transposes: W[dout][K] -> WT[K][dout] ----------------
__global__ __launch_bounds__(256) void k_transpose(const float* __restrict__ W,
                                                   float* __restrict__ WT,
                                                   int dout, int K) {
  int i = blockIdx.x * 256 + threadIdx.x;
  if (i >= K * dout) return;
  int k = i / dout, o = i - k * dout;
  WT[i] = W[o * K + k];
}

// Wp[15][256] -> WpT2[128][32] (padded): c<15 src half, 15<=c<30 dst half, else 0
__global__ __launch_bounds__(256) void k_wpT(const float* __restrict__ Wp,
                                             float* __restrict__ WpT2) {
  int i = blockIdx.x * 256 + threadIdx.x;
  if (i >= 128 * 32) return;
  int k = i / 32, c = i - k * 32;
  float v = 0.f;
  if (c < 15) v = Wp[c * 256 + k];
  else if (c < 30) v = Wp[(c - 15) * 256 + 128 + k];
  WpT2[i] = v;
}

// ---------------- segment sums via CSR (one wave per node) ----------------
__global__ __launch_bounds__(64) void k_eagg(const float* __restrict__ efeats,
                                             const int* __restrict__ csr_edge,
                                             const int* __restrict__ offs,
                                             float* __restrict__ eagg,
                                             float* __restrict__ deg) {
  int d = blockIdx.x, lane = threadIdx.x;
  int s = offs[d], t = offs[d + 1];
  float2 acc = make_float2(0.f, 0.f);
  float2 acc2 = make_float2(0.f, 0.f);
  int j = s;
  for (; j + 1 < t; j += 2) {
    int e0 = csr_edge[j], e1 = csr_edge[j + 1];
    float2 v0 = *reinterpret_cast<const float2*>(efeats + (size_t)e0 * 128 + lane * 2);
    float2 v1 = *reinterpret_cast<const float2*>(efeats + (size_t)e1 * 128 + lane * 2);
    acc.x += v0.x; acc.y += v0.y;
    acc2.x += v1.x; acc2.y += v1.y;
  }
  if (j < t) {
    int e0 = csr_edge[j];
    float2 v0 = *reinterpret_cast<const float2*>(efeats + (size_t)e0 * 128 + lane * 2);
    acc.x += v0.x; acc.y += v0.y;
  }
  acc.x += acc2.x; acc.y += acc2.y;
  *reinterpret_cast<float2*>(eagg + (size_t)d * 128 + lane * 2) = acc;
  if (lane == 0) deg[d] = (float)(t - s);
}

template <int DIN>
__global__ __launch_bounds__(64) void k_gather(const float* __restrict__ h,
                                               const int* __restrict__ csr_src,
                                               const int* __restrict__ offs,
                                               float* __restrict__ g) {
  constexpr int NV = (DIN + 63) / 64;
  int d = blockIdx.x, lane = threadIdx.x;
  float acc[NV];
#pragma unroll
  for (int v = 0; v < NV; ++v) acc[v] = 0.f;
  int s = offs[d], t = offs[d + 1];
  for (int j = s; j < t; ++j) {
    int sn = csr_src[j];
    const float* row = h + (size_t)sn * DIN;
#pragma unroll
    for (int v = 0; v < NV; ++v) {
      int k = lane + 64 * v;
      if (k < DIN) acc[v] += row[k];
    }
  }
#pragma unroll
  for (int v = 0; v < NV; ++v) {
    int k = lane + 64 * v;
    if (k < DIN) g[(size_t)d * DIN + k] = acc[v];
  }
}

// ---------------- tiled node GEMM ----------------
// Y[M][dout] = post( concat(A[M][KA], B[M][KB]) @ WT[K][dout] )
// 1 wave per block. BM=64, BN=64, BK=8, micro-tile 8x8 per thread.
// Requirements (all satisfied here): KA%8==0, (KA+KB)%8==0, dout%8==0,
// KA,KB,dout %4==0 for float4 alignment.
// MODE 0: y = acc/max(deg,1) + bias*(deg>0); MODE 1: relu(acc+bias); MODE 2: acc.
template <int MODE>
__global__ __launch_bounds__(64) void k_gemm_t(const float* __restrict__ A, int KA,
                                               const float* __restrict__ B, int KB,
                                               const float* __restrict__ WT,
                                               const float* __restrict__ bias,
                                               const float* __restrict__ deg,
                                               float* __restrict__ Y, int dout, int M) {
  __shared__ float As[2][8][64];
  __shared__ float Ws[2][8][64];
  const int tid = threadIdx.x;
  const int m0 = blockIdx.y * 64;
  const int n0 = blockIdx.x * 64;
  const int K = KA + KB;
  const int NT = K >> 3;

  // micro-tile coords
  const int tm = (tid & 7) * 8;
  const int tn = (tid >> 3) * 8;
  // staging coords
  const int sm = tid;                 // A-stage row within tile
  const int arow = min(m0 + sm, M - 1);
  const int wk = tid >> 3;            // W-stage k within tile
  const int wn = (tid & 7) * 8;       // W-stage col offset
  const bool wok = (n0 + wn) < dout;  // whole float8 valid (dout%8==0)

  float acc[8][8];
#pragma unroll
  for (int i = 0; i < 8; ++i)
#pragma unroll
    for (int j = 0; j < 8; ++j) acc[i][j] = 0.f;

  auto load_tile = [&](int t, float av[8], float4& w0, float4& w1) {
    const int k0 = t << 3;
    const float* P;
    int KP, kp;
    if (k0 < KA) { P = A; KP = KA; kp = k0; }
    else         { P = B; KP = KB; kp = k0 - KA; }
    const float* prow = P + (size_t)arow * KP + kp;
    float4 x0 = *reinterpret_cast<const float4*>(prow);
    float4 x1 = *reinterpret_cast<const float4*>(prow + 4);
    av[0] = x0.x; av[1] = x0.y; av[2] = x0.z; av[3] = x0.w;
    av[4] = x1.x; av[5] = x1.y; av[6] = x1.z; av[7] = x1.w;
    if (wok) {
      const float* wr = WT + (size_t)(k0 + wk) * dout + n0 + wn;
      w0 = *reinterpret_cast<const float4*>(wr);
      w1 = *reinterpret_cast<const float4*>(wr + 4);
    } else {
      w0 = make_float4(0.f, 0.f, 0.f, 0.f);
      w1 = w0;
    }
  };

  // stage tile 0
  {
    float av[8]; float4 w0, w1;
    load_tile(0, av, w0, w1);
#pragma unroll
    for (int kk = 0; kk < 8; ++kk) As[0][kk][sm] = av[kk];
    *reinterpret_cast<float4*>(&Ws[0][wk][wn]) = w0;
    *reinterpret_cast<float4*>(&Ws[0][wk][wn + 4]) = w1;
  }

  for (int t = 0; t < NT; ++t) {
    const int p = t & 1;
    float av[8]; float4 w0n, w1n;
    const bool more = (t + 1) < NT;
    if (more) load_tile(t + 1, av, w0n, w1n);  // globals in flight during compute
#pragma unroll
    for (int kk = 0; kk < 8; ++kk) {
      const float4 a0 = *reinterpret_cast<const float4*>(&As[p][kk][tm]);
      const float4 a1 = *reinterpret_cast<const float4*>(&As[p][kk][tm + 4]);
      const float4 b0 = *reinterpret_cast<const float4*>(&Ws[p][kk][tn]);
      const float4 b1 = *reinterpret_cast<const float4*>(&Ws[p][kk][tn + 4]);
      const float am[8] = {a0.x, a0.y, a0.z, a0.w, a1.x, a1.y, a1.z, a1.w};
      const float wm[8] = {b0.x, b0.y, b0.z, b0.w, b1.x, b1.y, b1.z, b1.w};
#pragma unroll
      for (int i = 0; i < 8; ++i)
#pragma unroll
        for (int j = 0; j < 8; ++j) acc[i][j] = fmaf(am[i], wm[j], acc[i][j]);
    }
    if (more) {
      const int q = p ^ 1;
#pragma unroll
      for (int kk = 0; kk < 8; ++kk) As[q][kk][sm] = av[kk];
      *reinterpret_cast<float4*>(&Ws[q][wk][wn]) = w0n;
      *reinterpret_cast<float4*>(&Ws[q][wk][wn + 4]) = w1n;
    }
  }

  // epilogue
  if ((n0 + tn) < dout) {
    float bv[8];
    if (MODE != 2) {
#pragma unroll
      for (int j = 0; j < 8; ++j) bv[j] = bias[n0 + tn + j];
    }
#pragma unroll
    for (int i = 0; i < 8; ++i) {
      const int r = m0 + tm + i;
      if (r < M) {
        float y[8];
        if constexpr (MODE == 0) {
          const float dg = deg[r];
          const float sc = 1.f / fmaxf(dg, 1.f);
          const float en = dg > 0.f ? 1.f : 0.f;
#pragma unroll
          for (int j = 0; j < 8; ++j) y[j] = acc[i][j] * sc + bv[j] * en;
        } else if constexpr (MODE == 1) {
#pragma unroll
          for (int j = 0; j < 8; ++j) y[j] = fmaxf(acc[i][j] + bv[j], 0.f);
        } else {
#pragma unroll
          for (int j = 0; j < 8; ++j) y[j] = acc[i][j];
        }
        float* yp = Y + (size_t)r * dout + n0 + tn;
        *reinterpret_cast<float4*>(yp) = make_float4(y[0], y[1], y[2], y[3]);
        *reinterpret_cast<float4*>(yp + 4) = make_float4(y[4], y[5], y[6], y[7]);
      }
    }
  }
}

// ---------------- edge output (hsd stride 32, src cols 0..14, dst cols 15..29) ----
__global__ __launch_bounds__(256) void k_edge_out(const int* __restrict__ src,
                                                  const int* __restrict__ dst,
                                                  const float* __restrict__ hsd,
                                                  const float* __restrict__ bp,
                                                  float* __restrict__ out, int E) {
  int i = blockIdx.x * 256 + threadIdx.x;
  if (i >= E * 15) return;
  int e = i / 15, c = i - e * 15;
  out[i] = hsd[(size_t)src[e] * 32 + c] + hsd[(size_t)dst[e] * 32 + 15 + c] + bp[c];
}

extern "C" void kernel_launch(void* const* d_in, const int* in_sizes, int n_in,
                              void* d_out, int out_size, void* d_ws, size_t ws_size,
                              hipStream_t stream) {
  const int N = 10000, E = 320000;
  const float* nfeats = (const float*)d_in[0];
  const float* efeats = (const float*)d_in[1];
  const int* src = (const int*)d_in[2];
  const int* dst = (const int*)d_in[3];
  const float* Wm1 = (const float*)d_in[4];
  const float* bm1 = (const float*)d_in[5];
  const float* Wa1 = (const float*)d_in[6];
  const float* ba1 = (const float*)d_in[7];
  const float* Wm2 = (const float*)d_in[8];
  const float* bm2 = (const float*)d_in[9];
  const float* Wa2 = (const float*)d_in[10];
  const float* ba2 = (const float*)d_in[11];
  const float* Wm3 = (const float*)d_in[12];
  const float* bm3 = (const float*)d_in[13];
  const float* Wa3 = (const float*)d_in[14];
  const float* ba3 = (const float*)d_in[15];
  const float* Wp = (const float*)d_in[16];
  const float* bp = (const float*)d_in[17];
  float* out = (float*)d_out;

  char* base = (char*)d_ws;
  size_t woff = 0;
  auto alloc = [&](size_t bytes) -> void* {
    void* p = base + woff;
    woff += (bytes + 255) & ~(size_t)255;
    return p;
  };
  int* cnt = (int*)alloc((size_t)N * 4);
  int* fill = (int*)alloc((size_t)N * 4);
  int* offs = (int*)alloc((size_t)(N + 1) * 4);
  int* csr_edge = (int*)alloc((size_t)E * 4);
  int* csr_src = (int*)alloc((size_t)E * 4);
  float* deg = (float*)alloc((size_t)N * 4);
  float* eagg = (float*)alloc((size_t)N * 128 * 4);
  float* hA = (float*)alloc((size_t)N * 152 * 4);
  float* hB = (float*)alloc((size_t)N * 152 * 4);
  float* g = (float*)alloc((size_t)N * 152 * 4);
  float* nmean = (float*)alloc((size_t)N * 152 * 4);
  float* hsd = (float*)alloc((size_t)N * 32 * 4);
  float* WmT1 = (float*)alloc((256 * 152 + 8) * 4);
  float* WaT1 = (float*)alloc((280 * 152 + 8) * 4);
  float* WmT2 = (float*)alloc((280 * 152 + 8) * 4);
  float* WaT2 = (float*)alloc((304 * 152 + 8) * 4);
  float* WmT3 = (float*)alloc((280 * 128 + 8) * 4);
  float* WaT3 = (float*)alloc((280 * 128 + 8) * 4);
  float* WpT2 = (float*)alloc((128 * 32 + 8) * 4);

  hipMemsetAsync(cnt, 0, (size_t)N * 4, stream);
  hipMemsetAsync(fill, 0, (size_t)N * 4, stream);

  // CSR build
  k_hist<<<cdiv(E, 256), 256, 0, stream>>>(dst, cnt, E);
  k_scan<<<1, 1024, 0, stream>>>(cnt, offs, N);
  k_scatter<<<cdiv(E, 256), 256, 0, stream>>>(src, dst, offs, fill, csr_edge, csr_src, E);

  // weight transposes (tiny)
  k_transpose<<<cdiv(256 * 152, 256), 256, 0, stream>>>(Wm1, WmT1, 152, 256);
  k_transpose<<<cdiv(280 * 152, 256), 256, 0, stream>>>(Wa1, WaT1, 152, 280);
  k_transpose<<<cdiv(280 * 152, 256), 256, 0, stream>>>(Wm2, WmT2, 152, 280);
  k_transpose<<<cdiv(304 * 152, 256), 256, 0, stream>>>(Wa2, WaT2, 152, 304);
  k_transpose<<<cdiv(280 * 128, 256), 256, 0, stream>>>(Wm3, WmT3, 128, 280);
  k_transpose<<<cdiv(280 * 128, 256), 256, 0, stream>>>(Wa3, WaT3, 128, 280);
  k_wpT<<<cdiv(128 * 32, 256), 256, 0, stream>>>(Wp, WpT2);

  // layer-independent edge-feature aggregation (the only big HBM read)
  k_eagg<<<N, 64, 0, stream>>>(efeats, csr_edge, offs, eagg, deg);

  const int RB = cdiv(N, 64);  // 157
  dim3 g152(cdiv(152, 64), RB);
  dim3 g128(cdiv(128, 64), RB);
  dim3 g32(1, RB);

  // layer 1: din=128 -> 152
  k_gather<128><<<N, 64, 0, stream>>>(nfeats, csr_src, offs, g);
  k_gemm_t<0><<<g152, 64, 0, stream>>>(g, 128, eagg, 128, WmT1, bm1, deg, nmean, 152, N);
  k_gemm_t<1><<<g152, 64, 0, stream>>>(nfeats, 128, nmean, 152, WaT1, ba1, nullptr, hA, 152, N);
  // layer 2: 152 -> 152
  k_gather<152><<<N, 64, 0, stream>>>(hA, csr_src, offs, g);
  k_gemm_t<0><<<g152, 64, 0, stream>>>(g, 152, eagg, 128, WmT2, bm2, deg, nmean, 152, N);
  k_gemm_t<1><<<g152, 64, 0, stream>>>(hA, 152, nmean, 152, WaT2, ba2, nullptr, hB, 152, N);
  // layer 3: 152 -> 128
  k_gather<152><<<N, 64, 0, stream>>>(hB, csr_src, offs, g);
  k_gemm_t<0><<<g128, 64, 0, stream>>>(g, 152, eagg, 128, WmT3, bm3, deg, nmean, 128, N);
  k_gemm_t<1><<<g128, 64, 0, stream>>>(hB, 152, nmean, 128, WaT3, ba3, nullptr, hA, 128, N);

  // edge predictor: hsd[n] = [h@Wp_src.T | h@Wp_dst.T] (padded to 32 cols)
  k_gemm_t<2><<<g32, 64, 0, stream>>>(hA, 128, nullptr, 0, WpT2, nullptr, nullptr, hsd, 32, N);
  k_edge_out<<<cdiv(E * 15, 256), 256, 0, stream>>>(src, dst, hsd, bp, out, E);
}

// Round 3
// 304.527 us; speedup vs baseline: 3.2745x; 1.9279x over previous
//
#include <hip/hip_runtime.h>
#include <hip/hip_bf16.h>
#include <cstdint>

// GraphSAGE 3-layer + edge predictor.
// Factoring: segsum(concat(h[src],e)@Wm.T+bm, dst) = g@Wmh.T + eagg@Wme.T + deg*bm
//   with g = segsum(h[src]), eagg = segsum(e) (layer-independent).
// GEMMs run on MFMA (16x16x32 bf16) with hi/lo split operands:
//   x = hi + lo (bf16 pair), y = hi*Whi + lo*Whi + hi*Wlo  (err ~2^-17).
// All node tensors stored as bf16 hi/lo planes, K padded to x32 (zeros).
// W pre-packed into B-fragment order with the SAME (lane,elem)->k map as the
// A-side loads -> result invariant to HW's internal k ordering.

static inline int cdiv(int a, int b) { return (a + b - 1) / b; }

typedef __attribute__((ext_vector_type(8))) short bf16x8;
typedef __attribute__((ext_vector_type(4))) float f32x4;

__device__ __forceinline__ ushort f2bf(float x) {
  union { float f; unsigned u; } c; c.f = x;
  unsigned r = c.u + 0x7FFFu + ((c.u >> 16) & 1u);
  return (ushort)(r >> 16);
}
__device__ __forceinline__ float bf2f(unsigned h) {
  union { unsigned u; float f; } c; c.u = h << 16;
  return c.f;
}

// ---------------- CSR build ----------------
__global__ __launch_bounds__(256) void k_hist(const int* __restrict__ dst,
                                              int* __restrict__ cnt, int E) {
  int e = blockIdx.x * 256 + threadIdx.x;
  if (e < E) atomicAdd(&cnt[dst[e]], 1);
}

__global__ __launch_bounds__(1024) void k_scan(const int* __restrict__ cnt,
                                               int* __restrict__ offs, int n) {
  __shared__ int smem[1024];
  const int t = threadIdx.x;
  const int base = t * 10;
  int c[10];
  int s = 0;
#pragma unroll
  for (int i = 0; i < 10; ++i) {
    int idx = base + i;
    int v = (idx < n) ? cnt[idx] : 0;
    s += v;
    c[i] = s;  // inclusive local prefix
  }
  smem[t] = s;
  __syncthreads();
  for (int ofs = 1; ofs < 1024; ofs <<= 1) {
    int add = (t >= ofs) ? smem[t - ofs] : 0;
    __syncthreads();
    smem[t] += add;
    __syncthreads();
  }
  int excl = smem[t] - s;
  if (t == 0) offs[0] = 0;
#pragma unroll
  for (int i = 0; i < 10; ++i) {
    int idx = base + i;
    if (idx < n) offs[idx + 1] = excl + c[i];
  }
}

__global__ __launch_bounds__(256) void k_scatter(const int* __restrict__ src,
                                                 const int* __restrict__ dst,
                                                 const int* __restrict__ offs,
                                                 int* __restrict__ fill,
                                                 int* __restrict__ csr_edge,
                                                 int* __restrict__ csr_src, int E) {
  int e = blockIdx.x * 256 + threadIdx.x;
  if (e < E) {
    int d = dst[e];
    int pos = offs[d] + atomicAdd(&fill[d], 1);
    csr_edge[pos] = e;
    csr_src[pos] = src[e];
  }
}

// ---------------- weight prep: fp32 W[dout][Korig] -> packed bf16 frag planes --
// Packed layout: frag index f = (kt*NG16 + g)*64 + lane; element j at f*8+j maps
// (k = kt*32 + (lane>>4)*8 + j, col = g*16 + (lane&15)). Concat k-space:
// kk<KApad -> A-part (orig k=kk if kk<KA else zero-pad), else B-part.
struct WDesc {
  const float* W; ushort* hi; ushort* lo;
  int dout, KA, KApad, KB, Korig, NG16, KT, pred;
};
struct WDescs { WDesc d[7]; };

__global__ __launch_bounds__(256) void k_prep_W(WDescs P) {
  const WDesc d = P.d[blockIdx.y];
  int tid = blockIdx.x * 256 + threadIdx.x;
  if (tid >= d.KT * d.NG16 * 64) return;
  int lane = tid & 63;
  int g = (tid >> 6) % d.NG16;
  int t = (tid >> 6) / d.NG16;
  int col = g * 16 + (lane & 15);
  int kbase = t * 32 + ((lane >> 4) * 8);
  size_t o = (size_t)tid * 8;
#pragma unroll
  for (int j = 0; j < 8; ++j) {
    int kk = kbase + j;
    float w = 0.f;
    if (!d.pred) {
      if (col < d.dout) {
        if (kk < d.KApad) {
          if (kk < d.KA) w = d.W[(size_t)col * d.Korig + kk];
        } else {
          int kb = kk - d.KApad;
          if (kb < d.KB) w = d.W[(size_t)col * d.Korig + d.KA + kb];
        }
      }
    } else {  // edge predictor: cols 0..14 src half, 15..29 dst half
      if (col < 15) w = d.W[(size_t)col * 256 + kk];
      else if (col < 30) w = d.W[(size_t)(col - 15) * 256 + 128 + kk];
    }
    ushort h = f2bf(w);
    d.hi[o + j] = h;
    d.lo[o + j] = f2bf(w - bf2f(h));
  }
}

// ---------------- nfeats fp32 -> hi/lo planes ----------------
__global__ __launch_bounds__(256) void k_prep_nf(const float* __restrict__ x,
                                                 ushort* __restrict__ hi,
                                                 ushort* __restrict__ lo, int n) {
  int i = blockIdx.x * 256 + threadIdx.x;
  if (i >= n) return;
  float v = x[i];
  ushort h = f2bf(v);
  hi[i] = h;
  lo[i] = f2bf(v - bf2f(h));
}

// ---------------- edge-feature aggregation (big HBM read) ----------------
__global__ __launch_bounds__(64) void k_eagg(const float* __restrict__ efeats,
                                             const int* __restrict__ csr_edge,
                                             const int* __restrict__ offs,
                                             ushort* __restrict__ ehi,
                                             ushort* __restrict__ elo,
                                             float* __restrict__ deg) {
  int d = blockIdx.x, lane = threadIdx.x;
  int s = offs[d], t = offs[d + 1];
  float2 acc = make_float2(0.f, 0.f), acc2 = make_float2(0.f, 0.f);
  int j = s;
  for (; j + 1 < t; j += 2) {
    int e0 = csr_edge[j], e1 = csr_edge[j + 1];
    float2 v0 = *reinterpret_cast<const float2*>(efeats + (size_t)e0 * 128 + lane * 2);
    float2 v1 = *reinterpret_cast<const float2*>(efeats + (size_t)e1 * 128 + lane * 2);
    acc.x += v0.x; acc.y += v0.y;
    acc2.x += v1.x; acc2.y += v1.y;
  }
  if (j < t) {
    int e0 = csr_edge[j];
    float2 v0 = *reinterpret_cast<const float2*>(efeats + (size_t)e0 * 128 + lane * 2);
    acc.x += v0.x; acc.y += v0.y;
  }
  acc.x += acc2.x; acc.y += acc2.y;
  size_t o = (size_t)d * 128 + lane * 2;
  ushort hx = f2bf(acc.x), hy = f2bf(acc.y);
  ehi[o] = hx; ehi[o + 1] = hy;
  elo[o] = f2bf(acc.x - bf2f(hx)); elo[o + 1] = f2bf(acc.y - bf2f(hy));
  if (lane == 0) deg[d] = (float)(t - s);
}

// ---------------- gather-sum of h[src] rows (hi/lo planes in & out) ----------
template <int KPAD>
__global__ __launch_bounds__(64) void k_gatherp(const ushort* __restrict__ hhi,
                                                const ushort* __restrict__ hlo,
                                                const int* __restrict__ csr_src,
                                                const int* __restrict__ offs,
                                                ushort* __restrict__ ghi,
                                                ushort* __restrict__ glo) {
  constexpr int PAIRS = KPAD / 2;           // 64 or 80
  constexpr int NV = (PAIRS + 63) / 64;     // 1 or 2
  int d = blockIdx.x, lane = threadIdx.x;
  int s = offs[d], t = offs[d + 1];
  float2 acc[NV], acc2[NV];
#pragma unroll
  for (int v = 0; v < NV; ++v) { acc[v] = make_float2(0.f, 0.f); acc2[v] = make_float2(0.f, 0.f); }
  int j = s;
  for (; j + 1 < t; j += 2) {
    int s0 = csr_src[j], s1 = csr_src[j + 1];
#pragma unroll
    for (int v = 0; v < NV; ++v) {
      int p = lane + 64 * v;
      if (p < PAIRS) {
        unsigned uh0 = *reinterpret_cast<const unsigned*>(hhi + (size_t)s0 * KPAD + 2 * p);
        unsigned ul0 = *reinterpret_cast<const unsigned*>(hlo + (size_t)s0 * KPAD + 2 * p);
        unsigned uh1 = *reinterpret_cast<const unsigned*>(hhi + (size_t)s1 * KPAD + 2 * p);
        unsigned ul1 = *reinterpret_cast<const unsigned*>(hlo + (size_t)s1 * KPAD + 2 * p);
        acc[v].x += bf2f(uh0 & 0xffffu) + bf2f(ul0 & 0xffffu);
        acc[v].y += bf2f(uh0 >> 16) + bf2f(ul0 >> 16);
        acc2[v].x += bf2f(uh1 & 0xffffu) + bf2f(ul1 & 0xffffu);
        acc2[v].y += bf2f(uh1 >> 16) + bf2f(ul1 >> 16);
      }
    }
  }
  if (j < t) {
    int s0 = csr_src[j];
#pragma unroll
    for (int v = 0; v < NV; ++v) {
      int p = lane + 64 * v;
      if (p < PAIRS) {
        unsigned uh0 = *reinterpret_cast<const unsigned*>(hhi + (size_t)s0 * KPAD + 2 * p);
        unsigned ul0 = *reinterpret_cast<const unsigned*>(hlo + (size_t)s0 * KPAD + 2 * p);
        acc[v].x += bf2f(uh0 & 0xffffu) + bf2f(ul0 & 0xffffu);
        acc[v].y += bf2f(uh0 >> 16) + bf2f(ul0 >> 16);
      }
    }
  }
#pragma unroll
  for (int v = 0; v < NV; ++v) {
    int p = lane + 64 * v;
    if (p < PAIRS) {
      float gx = acc[v].x + acc2[v].x;
      float gy = acc[v].y + acc2[v].y;
      size_t o = (size_t)d * KPAD + 2 * p;
      ushort hx = f2bf(gx), hy = f2bf(gy);
      ghi[o] = hx; ghi[o + 1] = hy;
      glo[o] = f2bf(gx - bf2f(hx)); glo[o + 1] = f2bf(gy - bf2f(hy));
    }
  }
}

// ---------------- MFMA GEMM: Y[M][dout] = post(concat(A,B) @ W) ----------------
// 1 wave/block, 32x32 output tile, K fully unrolled. hi/lo split: 3 MFMA/term.
// MODE 0: y = acc/max(deg,1) + bias*(deg>0) -> hi/lo planes (zero for pad cols)
// MODE 1: y = relu(acc + bias)              -> hi/lo planes (zero for pad cols)
// MODE 2: y = acc                           -> fp32 Yf
template <int KTA, int KTB, int MODE>
__global__ __launch_bounds__(64) void k_mfma(
    const ushort* __restrict__ Ahi, const ushort* __restrict__ Alo,
    const ushort* __restrict__ Bhi, const ushort* __restrict__ Blo,
    const ushort* __restrict__ Whi, const ushort* __restrict__ Wlo,
    const float* __restrict__ bias, const float* __restrict__ deg,
    ushort* __restrict__ Yhi, ushort* __restrict__ Ylo, float* __restrict__ Yf,
    int dout_real, int NG16, int OSTR, int M) {
  constexpr int KT = KTA + KTB;
  constexpr int SA = KTA * 32;
  constexpr int SB = (KTB > 0 ? KTB : 1) * 32;
  const int lane = threadIdx.x;
  const int ng0 = blockIdx.x * 2;
  const int row0 = blockIdx.y * 32;
  const int rA = lane & 15;
  const int kl = (lane >> 4) * 8;
  const int r0 = (row0 + rA < M) ? row0 + rA : M - 1;
  const int r1 = (row0 + 16 + rA < M) ? row0 + 16 + rA : M - 1;
  f32x4 acc00 = {0.f, 0.f, 0.f, 0.f}, acc01 = {0.f, 0.f, 0.f, 0.f};
  f32x4 acc10 = {0.f, 0.f, 0.f, 0.f}, acc11 = {0.f, 0.f, 0.f, 0.f};
#pragma unroll
  for (int kt = 0; kt < KT; ++kt) {
    bf16x8 a0h, a0l, a1h, a1l;
    if (KTB == 0 || kt < KTA) {
      const size_t o0 = (size_t)r0 * SA + kt * 32 + kl;
      const size_t o1 = (size_t)r1 * SA + kt * 32 + kl;
      a0h = *reinterpret_cast<const bf16x8*>(Ahi + o0);
      a0l = *reinterpret_cast<const bf16x8*>(Alo + o0);
      a1h = *reinterpret_cast<const bf16x8*>(Ahi + o1);
      a1l = *reinterpret_cast<const bf16x8*>(Alo + o1);
    } else {
      const int kb = (kt - KTA) * 32 + kl;
      const size_t o0 = (size_t)r0 * SB + kb;
      const size_t o1 = (size_t)r1 * SB + kb;
      a0h = *reinterpret_cast<const bf16x8*>(Bhi + o0);
      a0l = *reinterpret_cast<const bf16x8*>(Blo + o0);
      a1h = *reinterpret_cast<const bf16x8*>(Bhi + o1);
      a1l = *reinterpret_cast<const bf16x8*>(Blo + o1);
    }
    const size_t wb = ((size_t)(kt * NG16 + ng0) * 64 + lane) * 8;
    bf16x8 b0h = *reinterpret_cast<const bf16x8*>(Whi + wb);
    bf16x8 b0l = *reinterpret_cast<const bf16x8*>(Wlo + wb);
    bf16x8 b1h = *reinterpret_cast<const bf16x8*>(Whi + wb + 512);
    bf16x8 b1l = *reinterpret_cast<const bf16x8*>(Wlo + wb + 512);
    acc00 = __builtin_amdgcn_mfma_f32_16x16x32_bf16(a0h, b0h, acc00, 0, 0, 0);
    acc00 = __builtin_amdgcn_mfma_f32_16x16x32_bf16(a0l, b0h, acc00, 0, 0, 0);
    acc00 = __builtin_amdgcn_mfma_f32_16x16x32_bf16(a0h, b0l, acc00, 0, 0, 0);
    acc01 = __builtin_amdgcn_mfma_f32_16x16x32_bf16(a0h, b1h, acc01, 0, 0, 0);
    acc01 = __builtin_amdgcn_mfma_f32_16x16x32_bf16(a0l, b1h, acc01, 0, 0, 0);
    acc01 = __builtin_amdgcn_mfma_f32_16x16x32_bf16(a0h, b1l, acc01, 0, 0, 0);
    acc10 = __builtin_amdgcn_mfma_f32_16x16x32_bf16(a1h, b0h, acc10, 0, 0, 0);
    acc10 = __builtin_amdgcn_mfma_f32_16x16x32_bf16(a1l, b0h, acc10, 0, 0, 0);
    acc10 = __builtin_amdgcn_mfma_f32_16x16x32_bf16(a1h, b0l, acc10, 0, 0, 0);
    acc11 = __builtin_amdgcn_mfma_f32_16x16x32_bf16(a1h, b1h, acc11, 0, 0, 0);
    acc11 = __builtin_amdgcn_mfma_f32_16x16x32_bf16(a1l, b1h, acc11, 0, 0, 0);
    acc11 = __builtin_amdgcn_mfma_f32_16x16x32_bf16(a1h, b1l, acc11, 0, 0, 0);
  }
  // epilogue; C/D layout: col = lane&15, row = (lane>>4)*4 + reg  [m89-verified]
  const int colL = lane & 15;
#pragma unroll
  for (int ms = 0; ms < 2; ++ms) {
    const f32x4 aN0 = ms ? acc10 : acc00;
    const f32x4 aN1 = ms ? acc11 : acc01;
#pragma unroll
    for (int reg = 0; reg < 4; ++reg) {
      const int row = row0 + ms * 16 + (lane >> 4) * 4 + reg;
      if (row >= M) continue;
      float sc = 1.f, en = 0.f;
      if constexpr (MODE == 0) {
        float dg = deg[row];
        sc = 1.f / fmaxf(dg, 1.f);
        en = dg > 0.f ? 1.f : 0.f;
      }
#pragma unroll
      for (int ns = 0; ns < 2; ++ns) {
        const int col = (ng0 + ns) * 16 + colL;
        const float v = ns ? aN1[reg] : aN0[reg];
        if constexpr (MODE == 2) {
          Yf[(size_t)row * OSTR + col] = v;
        } else {
          float y;
          if constexpr (MODE == 0)
            y = (col < dout_real) ? v * sc + bias[col] * en : 0.f;
          else
            y = (col < dout_real) ? fmaxf(v + bias[col], 0.f) : 0.f;
          ushort h = f2bf(y);
          Yhi[(size_t)row * OSTR + col] = h;
          Ylo[(size_t)row * OSTR + col] = f2bf(y - bf2f(h));
        }
      }
    }
  }
}

// ---------------- edge output (hsd stride 32: cols 0..14 src, 15..29 dst) ------
__global__ __launch_bounds__(256) void k_edge_out(const int* __restrict__ src,
                                                  const int* __restrict__ dst,
                                                  const float* __restrict__ hsd,
                                                  const float* __restrict__ bp,
                                                  float* __restrict__ out, int E) {
  int i = blockIdx.x * 256 + threadIdx.x;
  if (i >= E * 15) return;
  int e = i / 15, c = i - e * 15;
  out[i] = hsd[(size_t)src[e] * 32 + c] + hsd[(size_t)dst[e] * 32 + 15 + c] + bp[c];
}

extern "C" void kernel_launch(void* const* d_in, const int* in_sizes, int n_in,
                              void* d_out, int out_size, void* d_ws, size_t ws_size,
                              hipStream_t stream) {
  const int N = 10000, E = 320000;
  const float* nfeats = (const float*)d_in[0];
  const float* efeats = (const float*)d_in[1];
  const int* src = (const int*)d_in[2];
  const int* dst = (const int*)d_in[3];
  const float* Wm1 = (const float*)d_in[4];
  const float* bm1 = (const float*)d_in[5];
  const float* Wa1 = (const float*)d_in[6];
  const float* ba1 = (const float*)d_in[7];
  const float* Wm2 = (const float*)d_in[8];
  const float* bm2 = (const float*)d_in[9];
  const float* Wa2 = (const float*)d_in[10];
  const float* ba2 = (const float*)d_in[11];
  const float* Wm3 = (const float*)d_in[12];
  const float* bm3 = (const float*)d_in[13];
  const float* Wa3 = (const float*)d_in[14];
  const float* ba3 = (const float*)d_in[15];
  const float* Wp = (const float*)d_in[16];
  const float* bp = (const float*)d_in[17];
  float* out = (float*)d_out;

  char* base = (char*)d_ws;
  size_t woff = 0;
  auto alloc = [&](size_t bytes) -> void* {
    void* p = base + woff;
    woff += (bytes + 255) & ~(size_t)255;
    return p;
  };
  int* cnt = (int*)alloc((size_t)N * 4);
  int* fill = (int*)alloc((size_t)N * 4);
  int* offs = (int*)alloc((size_t)(N + 1) * 4);
  int* csr_edge = (int*)alloc((size_t)E * 4);
  int* csr_src = (int*)alloc((size_t)E * 4);
  float* deg = (float*)alloc((size_t)N * 4);
  auto aplane = [&](int w) { return (ushort*)alloc((size_t)N * w * 2); };
  ushort* nf_hi = aplane(128);  ushort* nf_lo = aplane(128);
  ushort* ea_hi = aplane(128);  ushort* ea_lo = aplane(128);
  ushort* g_hi = aplane(160);   ushort* g_lo = aplane(160);
  ushort* nm_hi = aplane(160);  ushort* nm_lo = aplane(160);
  ushort* h1_hi = aplane(160);  ushort* h1_lo = aplane(160);
  ushort* h2_hi = aplane(160);  ushort* h2_lo = aplane(160);
  ushort* h3_hi = aplane(128);  ushort* h3_lo = aplane(128);
  float* hsd = (float*)alloc((size_t)N * 32 * 4);
  auto wpack = [&](int kt, int ng) { return (ushort*)alloc((size_t)kt * ng * 512 * 2); };
  ushort* Wm1h = wpack(8, 10);  ushort* Wm1l = wpack(8, 10);
  ushort* Wa1h = wpack(9, 10);  ushort* Wa1l = wpack(9, 10);
  ushort* Wm2h = wpack(9, 10);  ushort* Wm2l = wpack(9, 10);
  ushort* Wa2h = wpack(10, 10); ushort* Wa2l = wpack(10, 10);
  ushort* Wm3h = wpack(9, 8);   ushort* Wm3l = wpack(9, 8);
  ushort* Wa3h = wpack(9, 8);   ushort* Wa3l = wpack(9, 8);
  ushort* Wph = wpack(4, 2);    ushort* Wpl = wpack(4, 2);

  hipMemsetAsync(cnt, 0, (size_t)N * 4, stream);
  hipMemsetAsync(fill, 0, (size_t)N * 4, stream);

  // CSR build
  k_hist<<<cdiv(E, 256), 256, 0, stream>>>(dst, cnt, E);
  k_scan<<<1, 1024, 0, stream>>>(cnt, offs, N);
  k_scatter<<<cdiv(E, 256), 256, 0, stream>>>(src, dst, offs, fill, csr_edge, csr_src, E);

  // weight packs (one fused launch)          W, hi, lo, dout, KA, KApad, KB, Korig, NG16, KT, pred
  WDescs wd;
  wd.d[0] = {Wm1, Wm1h, Wm1l, 152, 128, 128, 128, 256, 10, 8, 0};
  wd.d[1] = {Wa1, Wa1h, Wa1l, 152, 128, 128, 152, 280, 10, 9, 0};
  wd.d[2] = {Wm2, Wm2h, Wm2l, 152, 152, 160, 128, 280, 10, 9, 0};
  wd.d[3] = {Wa2, Wa2h, Wa2l, 152, 152, 160, 152, 304, 10, 10, 0};
  wd.d[4] = {Wm3, Wm3h, Wm3l, 128, 152, 160, 128, 280, 8, 9, 0};
  wd.d[5] = {Wa3, Wa3h, Wa3l, 128, 152, 160, 128, 280, 8, 9, 0};
  wd.d[6] = {Wp, Wph, Wpl, 32, 128, 128, 0, 256, 2, 4, 1};
  k_prep_W<<<dim3(cdiv(10 * 10 * 64, 256), 7), 256, 0, stream>>>(wd);

  k_prep_nf<<<cdiv(N * 128, 256), 256, 0, stream>>>(nfeats, nf_hi, nf_lo, N * 128);

  // layer-independent edge-feature aggregation (the only big HBM read)
  k_eagg<<<N, 64, 0, stream>>>(efeats, csr_edge, offs, ea_hi, ea_lo, deg);

  const int MT = cdiv(N, 32);  // 313
  dim3 g5(5, MT), g4(4, MT), g1(1, MT);

  // layer 1: din=128 -> 152
  k_gatherp<128><<<N, 64, 0, stream>>>(nf_hi, nf_lo, csr_src, offs, g_hi, g_lo);
  k_mfma<4, 4, 0><<<g5, 64, 0, stream>>>(g_hi, g_lo, ea_hi, ea_lo, Wm1h, Wm1l,
                                         bm1, deg, nm_hi, nm_lo, nullptr, 152, 10, 160, N);
  k_mfma<4, 5, 1><<<g5, 64, 0, stream>>>(nf_hi, nf_lo, nm_hi, nm_lo, Wa1h, Wa1l,
                                         ba1, nullptr, h1_hi, h1_lo, nullptr, 152, 10, 160, N);
  // layer 2: 152 -> 152
  k_gatherp<160><<<N, 64, 0, stream>>>(h1_hi, h1_lo, csr_src, offs, g_hi, g_lo);
  k_mfma<5, 4, 0><<<g5, 64, 0, stream>>>(g_hi, g_lo, ea_hi, ea_lo, Wm2h, Wm2l,
                                         bm2, deg, nm_hi, nm_lo, nullptr, 152, 10, 160, N);
  k_mfma<5, 5, 1><<<g5, 64, 0, stream>>>(h1_hi, h1_lo, nm_hi, nm_lo, Wa2h, Wa2l,
                                         ba2, nullptr, h2_hi, h2_lo, nullptr, 152, 10, 160, N);
  // layer 3: 152 -> 128
  k_gatherp<160><<<N, 64, 0, stream>>>(h2_hi, h2_lo, csr_src, offs, g_hi, g_lo);
  k_mfma<5, 4, 0><<<g4, 64, 0, stream>>>(g_hi, g_lo, ea_hi, ea_lo, Wm3h, Wm3l,
                                         bm3, deg, nm_hi, nm_lo, nullptr, 128, 8, 128, N);
  k_mfma<5, 4, 1><<<g4, 64, 0, stream>>>(h2_hi, h2_lo, nm_hi, nm_lo, Wa3h, Wa3l,
                                         ba3, nullptr, h3_hi, h3_lo, nullptr, 128, 8, 128, N);

  // edge predictor: hsd = h3 @ [Wp_src | Wp_dst] (fp32 out, stride 32)
  k_mfma<4, 0, 2><<<g1, 64, 0, stream>>>(h3_hi, h3_lo, nullptr, nullptr, Wph, Wpl,
                                         nullptr, nullptr, nullptr, nullptr, hsd, 32, 2, 32, N);
  k_edge_out<<<cdiv(E * 15, 256), 256, 0, stream>>>(src, dst, hsd, bp, out, E);
}